// Round 1
// baseline (79.481 us; speedup 1.0000x reference)
//
#include <hip/hip_runtime.h>
#include <math.h>

#define BS 2
#define NV 12000
#define NP 100
#define NPILLAR (BS * NV)
#define OUT_CH 64
#define NTOTAL 2400000.0   // BS*NV*NP
#define VX 0.2f
#define VY 0.2f
#define XOFF 0.1f
#define YOFF (-39.9f)
#define BN_EPS 1e-3

__device__ __forceinline__ void build_f(const float4 p, float mx, float my, float mz,
                                        float cx, float cy, float* f) {
    f[0] = p.x; f[1] = p.y; f[2] = p.z; f[3] = p.w;
    f[4] = p.x - mx; f[5] = p.y - my; f[6] = p.z - mz;
    f[7] = p.x - cx; f[8] = p.y - cy;
}

// ---------------- Pass 1: global moments of the 9-dim augmented feature -----
// acc[0..8]  = sum f_i   over all valid points
// acc[9..53] = sum f_i*f_j (i<=j upper triangle)
__global__ __launch_bounds__(256) void pfn_stats(
    const float4* __restrict__ feat, const int* __restrict__ npts,
    const int* __restrict__ coors, double* __restrict__ acc)
{
    const int lane = threadIdx.x & 63;
    const int wave = threadIdx.x >> 6;
    const int gw = blockIdx.x * 4 + wave;
    const int nw = gridDim.x * 4;

    float s[54];
#pragma unroll
    for (int i = 0; i < 54; ++i) s[i] = 0.f;

    for (int pv = gw; pv < NPILLAR; pv += nw) {
        const float4* fp = feat + (size_t)pv * NP;
        float4 p0 = fp[lane];
        bool has1 = (lane + 64) < NP;
        float4 p1 = has1 ? fp[lane + 64] : make_float4(0.f, 0.f, 0.f, 0.f);

        // mean over ALL NP points (reference sums all P, divides by max(n,1))
        float sx = p0.x + p1.x, sy = p0.y + p1.y, sz = p0.z + p1.z;
#pragma unroll
        for (int off = 32; off; off >>= 1) {
            sx += __shfl_xor(sx, off);
            sy += __shfl_xor(sy, off);
            sz += __shfl_xor(sz, off);
        }
        int np_ = npts[pv];
        if (np_ > NP) np_ = NP;
        float inv = 1.f / fmaxf((float)np_, 1.f);
        float mx = sx * inv, my = sy * inv, mz = sz * inv;
        float cx = (float)coors[pv * 4 + 2] * VX + XOFF;
        float cy = (float)coors[pv * 4 + 1] * VY + YOFF;

        float f[9];
        if (lane < np_) {
            build_f(p0, mx, my, mz, cx, cy, f);
            int k = 9;
#pragma unroll
            for (int i = 0; i < 9; ++i) {
                s[i] += f[i];
#pragma unroll
                for (int j = i; j < 9; ++j) s[k++] += f[i] * f[j];
            }
        }
        if (lane + 64 < np_) {
            build_f(p1, mx, my, mz, cx, cy, f);
            int k = 9;
#pragma unroll
            for (int i = 0; i < 9; ++i) {
                s[i] += f[i];
#pragma unroll
                for (int j = i; j < 9; ++j) s[k++] += f[i] * f[j];
            }
        }
    }

    // wave reduce all 54 partials
#pragma unroll
    for (int i = 0; i < 54; ++i) {
#pragma unroll
        for (int off = 32; off; off >>= 1) s[i] += __shfl_xor(s[i], off);
    }

    __shared__ float red[4][54];
    if (lane == 0) {
#pragma unroll
        for (int i = 0; i < 54; ++i) red[wave][i] = s[i];
    }
    __syncthreads();
    if (threadIdx.x < 54) {
        float t = red[0][threadIdx.x] + red[1][threadIdx.x] +
                  red[2][threadIdx.x] + red[3][threadIdx.x];
        atomicAdd(&acc[threadIdx.x], (double)t);
    }
}

// ---------------- Pass 2: per-channel BN scale/shift from moments -----------
__global__ void pfn_finalize(const double* __restrict__ acc,
                             const float* __restrict__ W,
                             const float* __restrict__ gamma,
                             const float* __restrict__ beta,
                             float* __restrict__ scsh)
{
    int o = threadIdx.x;  // 64 threads
    double w[9];
#pragma unroll
    for (int i = 0; i < 9; ++i) w[i] = (double)W[i * OUT_CH + o];
    double mean = 0.0;
#pragma unroll
    for (int i = 0; i < 9; ++i) mean += acc[i] * w[i];
    mean /= NTOTAL;
    double ex2 = 0.0;
    int k = 9;
#pragma unroll
    for (int i = 0; i < 9; ++i) {
#pragma unroll
        for (int j = i; j < 9; ++j) {
            double c = acc[k++];
            ex2 += (i == j ? 1.0 : 2.0) * c * w[i] * w[j];
        }
    }
    ex2 /= NTOTAL;
    double var = ex2 - mean * mean;
    double scale = (double)gamma[o] / sqrt(var + BN_EPS);
    double shift = (double)beta[o] - mean * scale;
    scsh[o] = (float)scale;
    scsh[OUT_CH + o] = (float)shift;
}

// ---------------- Pass 3: recompute x, normalize, relu, max over points -----
// One wave per pillar; 4 waves (4 pillars) per block.
__global__ __launch_bounds__(256) void pfn_out(
    const float4* __restrict__ feat, const int* __restrict__ npts,
    const int* __restrict__ coors, const float* __restrict__ W,
    const float* __restrict__ scsh, float* __restrict__ out)
{
    __shared__ __align__(16) float flds[4][NP][12];  // stride 12 for aligned float4
    const int lane = threadIdx.x & 63;
    const int wave = threadIdx.x >> 6;
    const int pv = blockIdx.x * 4 + wave;  // grid = NPILLAR/4 exactly

    const float4* fp = feat + (size_t)pv * NP;
    float4 p0 = fp[lane];
    bool has1 = (lane + 64) < NP;
    float4 p1 = has1 ? fp[lane + 64] : make_float4(0.f, 0.f, 0.f, 0.f);
    float sx = p0.x + p1.x, sy = p0.y + p1.y, sz = p0.z + p1.z;
#pragma unroll
    for (int off = 32; off; off >>= 1) {
        sx += __shfl_xor(sx, off);
        sy += __shfl_xor(sy, off);
        sz += __shfl_xor(sz, off);
    }
    int np_ = npts[pv];
    if (np_ > NP) np_ = NP;
    float inv = 1.f / fmaxf((float)np_, 1.f);
    float mx = sx * inv, my = sy * inv, mz = sz * inv;
    float cx = (float)coors[pv * 4 + 2] * VX + XOFF;
    float cy = (float)coors[pv * 4 + 1] * VY + YOFF;

    float f[9];
    if (lane < np_) {
        build_f(p0, mx, my, mz, cx, cy, f);
        float4* dst = (float4*)&flds[wave][lane][0];
        dst[0] = make_float4(f[0], f[1], f[2], f[3]);
        dst[1] = make_float4(f[4], f[5], f[6], f[7]);
        flds[wave][lane][8] = f[8];
    }
    if (lane + 64 < np_) {
        build_f(p1, mx, my, mz, cx, cy, f);
        float4* dst = (float4*)&flds[wave][lane + 64][0];
        dst[0] = make_float4(f[0], f[1], f[2], f[3]);
        dst[1] = make_float4(f[4], f[5], f[6], f[7]);
        flds[wave][lane + 64][8] = f[8];
    }
    __syncthreads();

    // lane = output channel
    float scale = scsh[lane];
    float shift = scsh[OUT_CH + lane];
    float wc[9];
#pragma unroll
    for (int i = 0; i < 9; ++i) wc[i] = W[i * OUT_CH + lane] * scale;

    // padded points (always exist: np_ <= 99 < 100) contribute relu(shift)
    float acc = (np_ < NP) ? fmaxf(shift, 0.f) : -INFINITY;
    for (int p = 0; p < np_; ++p) {
        const float* fr = &flds[wave][p][0];
        float4 a = *(const float4*)fr;
        float4 b = *(const float4*)(fr + 4);
        float f8 = fr[8];
        float x = a.x * wc[0] + a.y * wc[1] + a.z * wc[2] + a.w * wc[3] +
                  b.x * wc[4] + b.y * wc[5] + b.z * wc[6] + b.w * wc[7] +
                  f8 * wc[8];
        acc = fmaxf(acc, fmaxf(x + shift, 0.f));
    }
    out[(size_t)pv * OUT_CH + lane] = acc;
}

extern "C" void kernel_launch(void* const* d_in, const int* in_sizes, int n_in,
                              void* d_out, int out_size, void* d_ws, size_t ws_size,
                              hipStream_t stream) {
    const float4* feat = (const float4*)d_in[0];
    const int* npts   = (const int*)d_in[1];
    const int* coors  = (const int*)d_in[2];
    const float* W    = (const float*)d_in[3];
    const float* gamma = (const float*)d_in[4];
    const float* beta  = (const float*)d_in[5];
    float* out = (float*)d_out;

    double* acc = (double*)d_ws;
    float* scsh = (float*)((char*)d_ws + 54 * sizeof(double));

    hipMemsetAsync(d_ws, 0, 54 * sizeof(double), stream);
    pfn_stats<<<256, 256, 0, stream>>>(feat, npts, coors, acc);
    pfn_finalize<<<1, 64, 0, stream>>>(acc, W, gamma, beta, scsh);
    pfn_out<<<NPILLAR / 4, 256, 0, stream>>>(feat, npts, coors, W, scsh, out);
}

// Round 2
// 48.857 us; speedup vs baseline: 1.6268x; 1.6268x over previous
//
#include <hip/hip_runtime.h>
#include <math.h>

#define NP 100
#define NPILLAR 24000
#define NBLK_MAIN (NPILLAR / 4)     // 6000 blocks, 4 pillars (waves) each
#define OUT_CH 64
#define NTOTAL 2400000.0            // bs*V*P
#define VXc 0.2f
#define VYc 0.2f
#define XOFF 0.1f
#define YOFF (-39.9f)
#define BN_EPS 1e-3
#define ROWS 128                    // padded point rows per pillar (>= NP)
#define RSTRIDE 20                  // shorts per LDS row (40 B -> <=2-way banks)

typedef __attribute__((ext_vector_type(8))) short bf16x8;
typedef __attribute__((ext_vector_type(4))) short short4v;
typedef __attribute__((ext_vector_type(16))) float f32x16;

__device__ __forceinline__ unsigned short f2bf(float x) {
    unsigned int b = __builtin_bit_cast(unsigned int, x);
    b += 0x7FFFu + ((b >> 16) & 1u);          // RNE
    return (unsigned short)(b >> 16);
}

__device__ __forceinline__ void stage_row(short* rowp, const float4 p, bool valid,
                                          float mx, float my, float mz,
                                          float cx, float cy) {
    unsigned short h[9];
    if (valid) {
        h[0] = f2bf(p.x); h[1] = f2bf(p.y); h[2] = f2bf(p.z); h[3] = f2bf(p.w);
        h[4] = f2bf(p.x - mx); h[5] = f2bf(p.y - my); h[6] = f2bf(p.z - mz);
        h[7] = f2bf(p.x - cx); h[8] = f2bf(p.y - cy);
    } else {
#pragma unroll
        for (int i = 0; i < 9; ++i) h[i] = 0;
    }
    short4v v0 = {(short)h[0], (short)h[1], (short)h[2], (short)h[3]};
    short4v v1 = {(short)h[4], (short)h[5], (short)h[6], (short)h[7]};
    short4v v2 = {(short)h[8], 0, 0, 0};
    short4v v3 = {0, 0, 0, 0};
    *(short4v*)(rowp + 0)  = v0;
    *(short4v*)(rowp + 4)  = v1;
    *(short4v*)(rowp + 8)  = v2;
    *(short4v*)(rowp + 12) = v3;
}

// One wave per pillar. MFMA 32x32x16 bf16: x = feats(9) @ W(9x64).
// Tracks per-(pillar,channel) max & min of x, and per-channel sum_x / sum_x2
// partials for the global BatchNorm statistics.
__global__ __launch_bounds__(256) void pfn_main(
    const float4* __restrict__ feat, const int* __restrict__ npts,
    const int* __restrict__ coors, const float* __restrict__ W,
    float* __restrict__ xmax_ws, float* __restrict__ xmin_ws,
    float* __restrict__ part)
{
    __shared__ short atile[4][ROWS * RSTRIDE];   // 20480 B
    __shared__ float red[4][128];                // 2048 B

    const int tid = threadIdx.x;
    const int lane = tid & 63;
    const int wv = tid >> 6;
    const int pv = blockIdx.x * 4 + wv;

    // ---- B fragments: lane holds B[k=(lane>>5)*8+i][col=(lane&31)+nt*32] ----
    const int col = lane & 31;
    const int kbase = (lane >> 5) * 8;
    bf16x8 bfr0, bfr1;
#pragma unroll
    for (int i = 0; i < 8; ++i) {
        int k = kbase + i;
        float w0 = (k < 9) ? W[k * OUT_CH + col] : 0.f;
        float w1 = (k < 9) ? W[k * OUT_CH + 32 + col] : 0.f;
        bfr0[i] = (short)f2bf(w0);
        bfr1[i] = (short)f2bf(w1);
    }

    // ---- load the pillar's points (coalesced float4) ----
    const float4* fp = feat + (size_t)pv * NP;
    float4 p0 = fp[lane];
    bool has1 = (lane + 64) < NP;
    float4 p1 = has1 ? fp[lane + 64] : make_float4(0.f, 0.f, 0.f, 0.f);

    // per-pillar mean over ALL NP points (reference semantics), div by max(n,1)
    float sx = p0.x + p1.x, sy = p0.y + p1.y, sz = p0.z + p1.z;
#pragma unroll
    for (int off = 32; off; off >>= 1) {
        sx += __shfl_xor(sx, off);
        sy += __shfl_xor(sy, off);
        sz += __shfl_xor(sz, off);
    }
    int np_ = npts[pv];
    if (np_ > NP) np_ = NP;
    float inv = 1.f / fmaxf((float)np_, 1.f);
    float mx = sx * inv, my = sy * inv, mz = sz * inv;
    float cx = (float)coors[pv * 4 + 2] * VXc + XOFF;
    float cy = (float)coors[pv * 4 + 1] * VYc + YOFF;

    // ---- stage A-tile rows lane and lane+64 (invalid rows -> zeros) ----
    short* base = atile[wv];
    stage_row(base + (size_t)lane * RSTRIDE, p0, lane < np_, mx, my, mz, cx, cy);
    stage_row(base + (size_t)(lane + 64) * RSTRIDE, p1, (lane + 64) < np_,
              mx, my, mz, cx, cy);
    __syncthreads();

    // ---- MFMA over ceil(np/32) M-tiles; zero rows give x=0 (harmless) ----
    f32x16 cz;
#pragma unroll
    for (int i = 0; i < 16; ++i) cz[i] = 0.f;

    float xmx0 = -INFINITY, xmx1 = -INFINITY;
    float xmn0 = INFINITY, xmn1 = INFINITY;
    float s10 = 0.f, s11 = 0.f, s20 = 0.f, s21 = 0.f;

    const int nmt = (np_ + 31) >> 5;
    const short* arow = base + (size_t)(lane & 31) * RSTRIDE + (lane >> 5) * 8;
    for (int mt = 0; mt < nmt; ++mt) {
        const short* pb = arow + (size_t)mt * 32 * RSTRIDE;
        short4v a0 = *(const short4v*)pb;
        short4v a1 = *(const short4v*)(pb + 4);
        bf16x8 afr = {a0[0], a0[1], a0[2], a0[3], a1[0], a1[1], a1[2], a1[3]};

        f32x16 c0 = __builtin_amdgcn_mfma_f32_32x32x16_bf16(afr, bfr0, cz, 0, 0, 0);
#pragma unroll
        for (int r = 0; r < 16; ++r) {
            float v = c0[r];
            xmx0 = fmaxf(xmx0, v);
            xmn0 = fminf(xmn0, v);
            s10 += v;
            s20 = fmaf(v, v, s20);
        }
        f32x16 c1 = __builtin_amdgcn_mfma_f32_32x32x16_bf16(afr, bfr1, cz, 0, 0, 0);
#pragma unroll
        for (int r = 0; r < 16; ++r) {
            float v = c1[r];
            xmx1 = fmaxf(xmx1, v);
            xmn1 = fminf(xmn1, v);
            s11 += v;
            s21 = fmaf(v, v, s21);
        }
    }

    // padded positions (np_ <= 99 < NP always) contribute x = 0
    if (np_ < NP) {
        xmx0 = fmaxf(xmx0, 0.f); xmx1 = fmaxf(xmx1, 0.f);
        xmn0 = fminf(xmn0, 0.f); xmn1 = fminf(xmn1, 0.f);
    }

    // combine the two row-halves (lanes l and l+32 share channel col)
    xmx0 = fmaxf(xmx0, __shfl_xor(xmx0, 32));
    xmx1 = fmaxf(xmx1, __shfl_xor(xmx1, 32));
    xmn0 = fminf(xmn0, __shfl_xor(xmn0, 32));
    xmn1 = fminf(xmn1, __shfl_xor(xmn1, 32));
    s10 += __shfl_xor(s10, 32);
    s11 += __shfl_xor(s11, 32);
    s20 += __shfl_xor(s20, 32);
    s21 += __shfl_xor(s21, 32);

    if (lane < 32) {
        float* xo = xmax_ws + (size_t)pv * OUT_CH;
        float* no = xmin_ws + (size_t)pv * OUT_CH;
        xo[lane] = xmx0; xo[32 + lane] = xmx1;
        no[lane] = xmn0; no[32 + lane] = xmn1;
        red[wv][lane] = s10; red[wv][32 + lane] = s11;
        red[wv][64 + lane] = s20; red[wv][96 + lane] = s21;
    }
    __syncthreads();
    if (tid < 128) {
        part[(size_t)blockIdx.x * 128 + tid] =
            red[0][tid] + red[1][tid] + red[2][tid] + red[3][tid];
    }
}

// Reduce per-block BN partials -> per-channel scale/shift. 64 blocks, one/channel.
__global__ void pfn_reduce(const float* __restrict__ part,
                           const float* __restrict__ gamma,
                           const float* __restrict__ beta,
                           float* __restrict__ scsh)
{
    const int c = blockIdx.x;
    double s1 = 0.0, s2 = 0.0;
    for (int i = threadIdx.x; i < NBLK_MAIN; i += 256) {
        s1 += (double)part[(size_t)i * 128 + c];
        s2 += (double)part[(size_t)i * 128 + 64 + c];
    }
#pragma unroll
    for (int off = 32; off; off >>= 1) {
        s1 += __shfl_xor(s1, off);
        s2 += __shfl_xor(s2, off);
    }
    __shared__ double r1[4], r2[4];
    const int lane = threadIdx.x & 63, wv = threadIdx.x >> 6;
    if (lane == 0) { r1[wv] = s1; r2[wv] = s2; }
    __syncthreads();
    if (threadIdx.x == 0) {
        double S1 = r1[0] + r1[1] + r1[2] + r1[3];
        double S2 = r2[0] + r2[1] + r2[2] + r2[3];
        double mean = S1 / NTOTAL;
        double var = S2 / NTOTAL - mean * mean;
        double scale = (double)gamma[c] / sqrt(var + BN_EPS);
        double shift = (double)beta[c] - mean * scale;
        scsh[c] = (float)scale;
        scsh[OUT_CH + c] = (float)shift;
    }
}

// out[pv][c] = relu(scale * (scale>=0 ? xmax : xmin) + shift)
__global__ __launch_bounds__(256) void pfn_write(
    const float* __restrict__ xmax_ws, const float* __restrict__ xmin_ws,
    const float* __restrict__ scsh, float* __restrict__ out)
{
    const int i = blockIdx.x * 256 + threadIdx.x;
    const int c = i & 63;
    float scale = scsh[c], shift = scsh[OUT_CH + c];
    float v = (scale >= 0.f) ? xmax_ws[i] : xmin_ws[i];
    out[i] = fmaxf(fmaf(scale, v, shift), 0.f);
}

extern "C" void kernel_launch(void* const* d_in, const int* in_sizes, int n_in,
                              void* d_out, int out_size, void* d_ws, size_t ws_size,
                              hipStream_t stream) {
    const float4* feat = (const float4*)d_in[0];
    const int* npts    = (const int*)d_in[1];
    const int* coors   = (const int*)d_in[2];
    const float* W     = (const float*)d_in[3];
    const float* gamma = (const float*)d_in[4];
    const float* beta  = (const float*)d_in[5];

    float* xmax_ws = (float*)d_ws;                       // 24000*64 f32
    float* xmin_ws = xmax_ws + (size_t)NPILLAR * OUT_CH; // 24000*64 f32
    float* part    = xmin_ws + (size_t)NPILLAR * OUT_CH; // 6000*128 f32
    float* scsh    = part + (size_t)NBLK_MAIN * 128;     // 128 f32

    pfn_main<<<NBLK_MAIN, 256, 0, stream>>>(feat, npts, coors, W,
                                            xmax_ws, xmin_ws, part);
    pfn_reduce<<<OUT_CH, 256, 0, stream>>>(part, gamma, beta, scsh);
    pfn_write<<<(NPILLAR * OUT_CH) / 256, 256, 0, stream>>>(xmax_ws, xmin_ws,
                                                            scsh, (float*)d_out);
}